// Round 12
// baseline (546.926 us; speedup 1.0000x reference)
//
#include <hip/hip_runtime.h>
#include <hip/hip_fp16.h>
#include <cstdint>
#include <cstddef>

// BiARMA: N=50000, E=800000, IN=64, HID=64, OUT=32, K=2 stacks, T=2 layers.
//  - gcn_norm factored into dinv pre/post scaling; xd = x*dinv precomputed
//  - Agg(xW) = Agg(x)W; stacks packed/merged; CSR on-device; gathers fused into GEMMs
//  - SLOT-PER-NODE waves (4 nodes/wave share LDS weight reads)
//  - fp16 gathered intermediates (round-11: FETCH 227->91MB, latency-bound now)
//  - THIS ROUND: fp16 half2-packed LDS weights -> LDS halved (k_t0 64->32KB,
//    k_t1 32->16KB, k2_t0 32->16KB, k2_t1 8->4KB) -> occupancy cap 5->8 blocks/CU;
//    one ds_read_b32 yields 2 weights. Grids resized to 8 blocks/CU residency.
//  - NO min-waves launch_bounds (round-5: forced VGPR 48 -> spills)

#define NN 50000
#define EE 800000
#define NG (NN / 4)  // 12500 groups of 4 nodes
#define NCHUNK ((NN + 255) / 256)  // 196

__device__ __forceinline__ float rl(float v, int l) {
  return __int_as_float(__builtin_amdgcn_readlane(__float_as_int(v), l));
}

// feature c of node-slot i (both compile-time): lives in lane i*16+(c>>2), comp c&3
__device__ __forceinline__ float slotb(const float4& a, int i, int c) {
  int sl = i * 16 + (c >> 2);
  switch (c & 3) {
    case 0: return rl(a.x, sl);
    case 1: return rl(a.y, sl);
    case 2: return rl(a.z, sl);
    default: return rl(a.w, sl);
  }
}

// accumulate 4 fp16 values (packed in uint2) scaled by m into a float4
__device__ __forceinline__ void addh4(float4& a, uint2 q, float m) {
  __half2 h0 = __builtin_bit_cast(__half2, q.x);
  __half2 h1 = __builtin_bit_cast(__half2, q.y);
  float2 f0 = __half22float2(h0);
  float2 f1 = __half22float2(h1);
  a.x = fmaf(f0.x, m, a.x); a.y = fmaf(f0.y, m, a.y);
  a.z = fmaf(f1.x, m, a.z); a.w = fmaf(f1.y, m, a.w);
}

__device__ __forceinline__ unsigned short f2h(float v) {
  return __builtin_bit_cast(unsigned short, __float2half(v));
}

__device__ __forceinline__ __half2 pack2(float a, float b) {
  return __halves2half2(__float2half(a), __float2half(b));
}

// ---------------- CSR build ----------------

__global__ __launch_bounds__(256) void k_degree(const int* __restrict__ dst,
                                                int* __restrict__ deg) {
  int i = blockIdx.x * 256 + threadIdx.x;
  if (i < EE) atomicAdd(&deg[dst[i]], 1);
}

__global__ __launch_bounds__(256) void k_part(const int* __restrict__ deg,
                                              int* __restrict__ partial) {
  int i = blockIdx.x * 256 + threadIdx.x;
  int v = (i < NN) ? deg[i] : 0;
#pragma unroll
  for (int off = 1; off < 64; off <<= 1) v += __shfl_xor(v, off);
  __shared__ int wsum[4];
  if ((threadIdx.x & 63) == 0) wsum[threadIdx.x >> 6] = v;
  __syncthreads();
  if (threadIdx.x == 0) partial[blockIdx.x] = wsum[0] + wsum[1] + wsum[2] + wsum[3];
}

__global__ __launch_bounds__(256) void k_scanp(const int* __restrict__ partial,
                                               int* __restrict__ chunkbase) {
  __shared__ int sc[256];
  int t = threadIdx.x;
  int v = (t < NCHUNK) ? partial[t] : 0;
  sc[t] = v;
  __syncthreads();
  for (int off = 1; off < 256; off <<= 1) {
    int u = (t >= off) ? sc[t - off] : 0;
    __syncthreads();
    sc[t] += u;
    __syncthreads();
  }
  if (t < NCHUNK) chunkbase[t] = sc[t] - v;  // exclusive
}

__global__ __launch_bounds__(256) void k_rows(const int* __restrict__ deg,
                                              const int* __restrict__ chunkbase,
                                              int* __restrict__ rowstart,
                                              float* __restrict__ dinv,
                                              int* __restrict__ cursor) {
  __shared__ int sc[256];
  int t = threadIdx.x;
  int i = blockIdx.x * 256 + t;
  int d = (i < NN) ? deg[i] : 0;
  sc[t] = d;
  __syncthreads();
  for (int off = 1; off < 256; off <<= 1) {
    int u = (t >= off) ? sc[t - off] : 0;
    __syncthreads();
    sc[t] += u;
    __syncthreads();
  }
  if (i < NN) {
    rowstart[i] = chunkbase[blockIdx.x] + sc[t] - d;
    dinv[i] = (d > 0) ? rsqrtf((float)d) : 0.f;
    cursor[i] = 0;
  }
  if (blockIdx.x == 0 && t == 0) rowstart[NN] = EE;
}

__global__ __launch_bounds__(256) void k_fill(const int* __restrict__ src,
                                              const int* __restrict__ dst,
                                              const int* __restrict__ rowstart,
                                              int* __restrict__ cursor,
                                              int* __restrict__ csr) {
  int i = blockIdx.x * 256 + threadIdx.x;
  if (i < EE) {
    int d = dst[i];
    int pos = rowstart[d] + atomicAdd(&cursor[d], 1);
    csr[pos] = src[i];
  }
}

// ---------------- xd = x * dinv[n] ----------------

__global__ __launch_bounds__(256) void k_xd(const float* __restrict__ x,
                                            const float* __restrict__ dinv,
                                            float* __restrict__ xd) {
  int i = blockIdx.x * 256 + threadIdx.x;  // over NN*16 float4s
  if (i < NN * 16) {
    int n = i >> 4;
    float d = dinv[n];
    float4 v = ((const float4*)x)[i];
    v.x *= d; v.y *= d; v.z *= d; v.w *= d;
    ((float4*)xd)[i] = v;
  }
}

// ---- shared gather prologue: per-lane j/end for node base+es, uniform trip count ----
#define GATHER_SETUP(base)                                  \
  int n = (base) + es;                                      \
  int j = rowstart[n];                                      \
  int end = rowstart[n + 1];                                \
  int dg = end - j;                                         \
  int mtmp = max(dg, __shfl_xor(dg, 16));                   \
  mtmp = max(mtmp, __shfl_xor(mtmp, 32));                   \
  int mx = __builtin_amdgcn_readfirstlane(mtmp);

// masked src select: row 0 (cache-hot) when out of range
#define EDGE2                                               \
  int s0 = (j < end) ? csr[min(j, EE - 1)] : 0;             \
  int s1 = (j + 1 < end) ? csr[min(j + 1, EE - 1)] : 0;     \
  float m0 = (j < end) ? 1.f : 0.f;                         \
  float m1 = (j + 1 < end) ? 1.f : 0.f;

// ---------------- agg(xd) * dinv[n] -> aggxs [N,64] fp32 ----------------

__global__ __launch_bounds__(256) void k_aggx(const float* __restrict__ xd,
                                              const float* __restrict__ dinv,
                                              const int* __restrict__ rowstart,
                                              const int* __restrict__ csr,
                                              float* __restrict__ outp) {
  int lane = threadIdx.x & 63;
  int f4 = lane & 15, es = lane >> 4;
  int wg = (blockIdx.x * 256 + threadIdx.x) >> 6;
  int nwv = (gridDim.x * 256) >> 6;
  const float4* x4 = (const float4*)xd;
  for (int g = wg; g < NG; g += nwv) {
    int base = g * 4;
    GATHER_SETUP(base);
    float4 a = {0.f, 0.f, 0.f, 0.f};
    for (int it = 0; it < mx; it += 2) {
      EDGE2;
      float4 v0 = x4[(size_t)s0 * 16 + f4];
      float4 v1 = x4[(size_t)s1 * 16 + f4];
      a.x = fmaf(v0.x, m0, a.x); a.y = fmaf(v0.y, m0, a.y);
      a.z = fmaf(v0.z, m0, a.z); a.w = fmaf(v0.w, m0, a.w);
      a.x = fmaf(v1.x, m1, a.x); a.y = fmaf(v1.y, m1, a.y);
      a.z = fmaf(v1.z, m1, a.z); a.w = fmaf(v1.w, m1, a.w);
      j += 2;
    }
    float dn = dinv[n];
    a.x *= dn; a.y *= dn; a.z *= dn; a.w *= dn;
    ((float4*)outp)[(size_t)n * 16 + f4] = a;
  }
}

// ---------------- ARMA1 t=0, both stacks -> root01 fp32, s01h fp16 ----------------
// LDS: weights as half2 packed by stack -> 32KB total (was 64KB).

__global__ __launch_bounds__(256) void k_t0(const float* __restrict__ x,
                                            const float* __restrict__ aggxs,
                                            const float* __restrict__ initW,
                                            const float* __restrict__ rootW,
                                            const float* __restrict__ bias,
                                            const float* __restrict__ dinv,
                                            float* __restrict__ root01,
                                            unsigned short* __restrict__ s01h) {
  __shared__ __half2 Wi2[4096];
  __shared__ __half2 Wr2[4096];
  for (int i = threadIdx.x; i < 4096; i += 256) {
    Wi2[i] = pack2(initW[i], initW[4096 + i]);
    Wr2[i] = pack2(rootW[i], rootW[4096 + i]);
  }
  __syncthreads();
  int lane = threadIdx.x & 63;
  float b_0 = bias[lane], b_1 = bias[64 + lane];
  int wid = (blockIdx.x * 256 + threadIdx.x) >> 6;
  int nw = (gridDim.x * 256) >> 6;
  for (int n = wid; n < NN; n += nw) {
    float dn = dinv[n];
    float xv = x[(size_t)n * 64 + lane];
    float gv = aggxs[(size_t)n * 64 + lane];
    float r0 = b_0, r1 = b_1;
    float i0 = 0.f, i1 = 0.f;
#pragma unroll
    for (int c = 0; c < 64; c++) {
      float xc = rl(xv, c), gc = rl(gv, c);
      float2 wr = __half22float2(Wr2[c * 64 + lane]);
      float2 wi = __half22float2(Wi2[c * 64 + lane]);
      r0 = fmaf(xc, wr.x, r0);
      r1 = fmaf(xc, wr.y, r1);
      i0 = fmaf(gc, wi.x, i0);
      i1 = fmaf(gc, wi.y, i1);
    }
    size_t b = (size_t)n * 128 + lane;
    root01[b] = r0;
    root01[b + 64] = r1;
    s01h[b] = f2h(fmaxf(i0 + r0, 0.f) * dn);
    s01h[b + 64] = f2h(fmaxf(i1 + r1, 0.f) * dn);
  }
}

// ---------------- ARMA1 t=1 fused: gather s01h + GEMM + h (4 nodes/wave) ----------
// LDS: W as half2 packed by stack -> 16KB (was 32KB); one read = both stacks.

__global__ __launch_bounds__(256) void k_t1(const unsigned short* __restrict__ s01h,
                                            const float* __restrict__ root01,
                                            const float* __restrict__ W,
                                            const float* __restrict__ dinv,
                                            const int* __restrict__ rowstart,
                                            const int* __restrict__ csr,
                                            float* __restrict__ h,
                                            unsigned short* __restrict__ hsh) {
  __shared__ __half2 Wh2[4096];
  for (int i = threadIdx.x; i < 4096; i += 256)
    Wh2[i] = pack2(W[i], W[4096 + i]);
  __syncthreads();
  int lane = threadIdx.x & 63;
  int f4 = lane & 15, es = lane >> 4;
  int wg = (blockIdx.x * 256 + threadIdx.x) >> 6;
  int nwv = (gridDim.x * 256) >> 6;
  for (int g = wg; g < NG; g += nwv) {
    int base = g * 4;
    GATHER_SETUP(base);
    float4 a = {0.f, 0.f, 0.f, 0.f}, b = {0.f, 0.f, 0.f, 0.f};
    for (int it = 0; it < mx; it += 2) {
      EDGE2;
      const uint2* r0 = (const uint2*)(s01h + (size_t)s0 * 128);
      const uint2* r1 = (const uint2*)(s01h + (size_t)s1 * 128);
      uint2 q00 = r0[f4], q01 = r0[16 + f4];
      uint2 q10 = r1[f4], q11 = r1[16 + f4];
      addh4(a, q00, m0); addh4(b, q01, m0);
      addh4(a, q10, m1); addh4(b, q11, m1);
      j += 2;
    }
    // GEMM: 4 nodes share each LDS weight read; 1 read = both stacks' weights
    float c0[4] = {0.f, 0.f, 0.f, 0.f}, c1[4] = {0.f, 0.f, 0.f, 0.f};
#pragma unroll
    for (int c = 0; c < 64; c++) {
      float2 w = __half22float2(Wh2[c * 64 + lane]);
#pragma unroll
      for (int i = 0; i < 4; i++) {
        c0[i] = fmaf(slotb(a, i, c), w.x, c0[i]);
        c1[i] = fmaf(slotb(b, i, c), w.y, c1[i]);
      }
    }
    float dnl = dinv[n];
#pragma unroll
    for (int i = 0; i < 4; i++) {
      float dni = rl(dnl, i * 16);
      size_t bb = (size_t)(base + i) * 128 + lane;
      float o0 = fmaxf(fmaf(dni, c0[i], root01[bb]), 0.f);
      float o1 = fmaxf(fmaf(dni, c1[i], root01[bb + 64]), 0.f);
      float hv = 0.5f * (o0 + o1);
      h[(size_t)(base + i) * 64 + lane] = hv;
      hsh[(size_t)(base + i) * 64 + lane] = f2h(hv * dni);
    }
  }
}

// ---------------- ARMA2 t=0 fused: gather hsh + GEMM (stacks packed) ----------------
// LDS: weights half2 packed by c-pair -> 16KB (was 32KB).

__global__ __launch_bounds__(256) void k2_t0(const float* __restrict__ h,
                                             const unsigned short* __restrict__ hsh,
                                             const float* __restrict__ initW2,
                                             const float* __restrict__ rootW2,
                                             const float* __restrict__ b2,
                                             const float* __restrict__ dinv,
                                             const int* __restrict__ rowstart,
                                             const int* __restrict__ csr,
                                             float* __restrict__ root2,
                                             unsigned short* __restrict__ s2h) {
  __shared__ __half2 Wi2[2048];  // [k][cpair][col]
  __shared__ __half2 Wr2[2048];
  for (int idx = threadIdx.x; idx < 2048; idx += 256) {
    int k = idx >> 10, rem = idx & 1023, cp = rem >> 5, col = rem & 31;
    int b0 = k * 2048 + (2 * cp) * 32 + col;
    Wi2[idx] = pack2(initW2[b0], initW2[b0 + 32]);
    Wr2[idx] = pack2(rootW2[b0], rootW2[b0 + 32]);
  }
  __syncthreads();
  int lane = threadIdx.x & 63;
  int f4 = lane & 15, es = lane >> 4;
  int k = lane >> 5, col = lane & 31;
  float bv = b2[lane];
  int wg = (blockIdx.x * 256 + threadIdx.x) >> 6;
  int nwv = (gridDim.x * 256) >> 6;
  for (int g = wg; g < NG; g += nwv) {
    int base = g * 4;
    GATHER_SETUP(base);
    float4 a = {0.f, 0.f, 0.f, 0.f};
    for (int it = 0; it < mx; it += 2) {
      EDGE2;
      uint2 q0 = ((const uint2*)(hsh + (size_t)s0 * 64))[f4];
      uint2 q1 = ((const uint2*)(hsh + (size_t)s1 * 64))[f4];
      addh4(a, q0, m0);
      addh4(a, q1, m1);
      j += 2;
    }
    float hv[4];
#pragma unroll
    for (int i = 0; i < 4; i++) hv[i] = h[(size_t)(base + i) * 64 + lane];
    float aR[4] = {bv, bv, bv, bv}, aI[4] = {0.f, 0.f, 0.f, 0.f};
#pragma unroll
    for (int c = 0; c < 64; c += 2) {
      float2 wr = __half22float2(Wr2[k * 1024 + (c >> 1) * 32 + col]);
      float2 wi = __half22float2(Wi2[k * 1024 + (c >> 1) * 32 + col]);
#pragma unroll
      for (int i = 0; i < 4; i++) {
        aR[i] = fmaf(rl(hv[i], c), wr.x, aR[i]);
        aR[i] = fmaf(rl(hv[i], c + 1), wr.y, aR[i]);
        aI[i] = fmaf(slotb(a, i, c), wi.x, aI[i]);
        aI[i] = fmaf(slotb(a, i, c + 1), wi.y, aI[i]);
      }
    }
    float dnl = dinv[n];
#pragma unroll
    for (int i = 0; i < 4; i++) {
      float dni = rl(dnl, i * 16);
      float o = fmaxf(fmaf(dni, aI[i], aR[i]), 0.f);
      root2[(size_t)(base + i) * 64 + lane] = aR[i];
      s2h[(size_t)(base + i) * 64 + lane] = f2h(o * dni);
    }
  }
}

// ---------------- ARMA2 t=1 fused: gather s2h + GEMM + mean -> out ----------------
// LDS: weights half2 packed by c-pair -> 4KB (was 8KB).

__global__ __launch_bounds__(256) void k2_t1(const unsigned short* __restrict__ s2h,
                                             const float* __restrict__ root2,
                                             const float* __restrict__ W2,
                                             const float* __restrict__ dinv,
                                             const int* __restrict__ rowstart,
                                             const int* __restrict__ csr,
                                             float* __restrict__ outp) {
  __shared__ __half2 Ws2[1024];  // [k][cpair][col]
  for (int idx = threadIdx.x; idx < 1024; idx += 256) {
    int k = idx >> 9, rem = idx & 511, cp = rem >> 5, col = rem & 31;
    int b0 = k * 1024 + (2 * cp) * 32 + col;
    Ws2[idx] = pack2(W2[b0], W2[b0 + 32]);
  }
  __syncthreads();
  int lane = threadIdx.x & 63;
  int f4 = lane & 15, es = lane >> 4;
  int k = lane >> 5, col = lane & 31;
  int wg = (blockIdx.x * 256 + threadIdx.x) >> 6;
  int nwv = (gridDim.x * 256) >> 6;
  for (int g = wg; g < NG; g += nwv) {
    int base = g * 4;
    GATHER_SETUP(base);
    float4 a = {0.f, 0.f, 0.f, 0.f};
    for (int it = 0; it < mx; it += 2) {
      EDGE2;
      uint2 q0 = ((const uint2*)(s2h + (size_t)s0 * 64))[f4];
      uint2 q1 = ((const uint2*)(s2h + (size_t)s1 * 64))[f4];
      addh4(a, q0, m0);
      addh4(a, q1, m1);
      j += 2;
    }
    float acc[4] = {0.f, 0.f, 0.f, 0.f};
#pragma unroll
    for (int c = 0; c < 32; c += 2) {
      float2 w = __half22float2(Ws2[k * 512 + (c >> 1) * 32 + col]);
#pragma unroll
      for (int i = 0; i < 4; i++) {
        float pa = (lane < 32) ? slotb(a, i, c) : slotb(a, i, 32 + c);
        float pb = (lane < 32) ? slotb(a, i, c + 1) : slotb(a, i, 33 + c);
        acc[i] = fmaf(pa, w.x, acc[i]);
        acc[i] = fmaf(pb, w.y, acc[i]);
      }
    }
    float dnl = dinv[n];
#pragma unroll
    for (int i = 0; i < 4; i++) {
      float dni = rl(dnl, i * 16);
      float o = fmaxf(fmaf(dni, acc[i], root2[(size_t)(base + i) * 64 + lane]), 0.f);
      o += __shfl_xor(o, 32);
      if (lane < 32) outp[(size_t)(base + i) * 32 + col] = 0.5f * o;
    }
  }
}

// ---------------- host launch ----------------

extern "C" void kernel_launch(void* const* d_in, const int* in_sizes, int n_in,
                              void* d_out, int out_size, void* d_ws, size_t ws_size,
                              hipStream_t stream) {
  const float* x = (const float*)d_in[0];
  const int* edge_index = (const int*)d_in[1];
  const float* initW1 = (const float*)d_in[2];
  const float* w1 = (const float*)d_in[3];
  const float* rootW1 = (const float*)d_in[4];
  const float* b1 = (const float*)d_in[5];
  const float* initW2 = (const float*)d_in[6];
  const float* w2 = (const float*)d_in[7];
  const float* rootW2 = (const float*)d_in[8];
  const float* b2 = (const float*)d_in[9];
  float* out = (float*)d_out;

  const int* src = edge_index;
  const int* dst = edge_index + EE;

  size_t off = 0;
  auto carve = [&](size_t bytes) {
    size_t r = off;
    off = (off + bytes + 255) & ~(size_t)255;
    return r;
  };
  char* ws = (char*)d_ws;
  int* deg = (int*)(ws + carve((size_t)NN * 4));
  int* rowstart = (int*)(ws + carve((size_t)(NN + 1) * 4));
  int* csr = (int*)(ws + carve((size_t)EE * 4));
  float* dinv = (float*)(ws + carve((size_t)NN * 4));
  int* cursor = (int*)(ws + carve((size_t)NN * 4));
  int* partial = (int*)(ws + carve(256 * 4));
  int* chunkbase = (int*)(ws + carve(256 * 4));
  float* Bxd = (float*)(ws + carve((size_t)NN * 64 * 4));            // xd
  float* B1 = (float*)(ws + carve((size_t)NN * 64 * 4));             // aggxs, later h
  float* B2 = (float*)(ws + carve((size_t)NN * 128 * 4));            // root01, later root2
  unsigned short* H1 = (unsigned short*)(ws + carve((size_t)NN * 128 * 2));  // s01h, later s2h
  unsigned short* H2 = (unsigned short*)(ws + carve((size_t)NN * 64 * 2));   // hsh
  (void)ws_size; (void)in_sizes; (void)n_in; (void)out_size;

  const int EB = (EE + 255) / 256;

  hipMemsetAsync(deg, 0, (size_t)NN * 4, stream);
  k_degree<<<EB, 256, 0, stream>>>(dst, deg);
  k_part<<<NCHUNK, 256, 0, stream>>>(deg, partial);
  k_scanp<<<1, 256, 0, stream>>>(partial, chunkbase);
  k_rows<<<NCHUNK, 256, 0, stream>>>(deg, chunkbase, rowstart, dinv, cursor);
  k_fill<<<EB, 256, 0, stream>>>(src, dst, rowstart, cursor, csr);

  k_xd<<<(NN * 16 + 255) / 256, 256, 0, stream>>>(x, dinv, Bxd);
  k_aggx<<<2048, 256, 0, stream>>>(Bxd, dinv, rowstart, csr, B1);
  k_t0<<<1280, 256, 0, stream>>>(x, B1, initW1, rootW1, b1, dinv, B2, H1);
  k_t1<<<2048, 256, 0, stream>>>(H1, B2, w1, dinv, rowstart, csr, B1, H2);
  k2_t0<<<2048, 256, 0, stream>>>(B1, H2, initW2, rootW2, b2, dinv, rowstart, csr, B2, H1);
  k2_t1<<<2048, 256, 0, stream>>>(H1, B2, w2, dinv, rowstart, csr, out);
}

// Round 14
// 485.071 us; speedup vs baseline: 1.1275x; 1.1275x over previous
//
#include <hip/hip_runtime.h>
#include <hip/hip_fp16.h>
#include <cstdint>
#include <cstddef>

// BiARMA: N=50000, E=800000, IN=64, HID=64, OUT=32, K=2 stacks, T=2 layers.
//  - gcn_norm factored into dinv pre/post scaling; xd = x*dinv precomputed
//  - Agg(xW) = Agg(x)W; stacks packed/merged; CSR on-device; gathers fused into GEMMs
//  - SLOT-PER-NODE waves (4 nodes/wave share LDS weight reads)
//  - fp16 gathered intermediates; half2 LDS weights packed BY STACK everywhere
//    (round-12 lesson: c-pair packing doubled slotb chains -> VGPR 92 -> 123us k2_t1)
//  - natural divergent gather loops (no uniform-trip mask: saves 4 VALU/edge + junk loads)
//  - NO min-waves launch_bounds (round-5: forced VGPR 48 -> spills)

#define NN 50000
#define EE 800000
#define NG (NN / 4)  // 12500 groups of 4 nodes
#define NCHUNK ((NN + 255) / 256)  // 196

__device__ __forceinline__ float rl(float v, int l) {
  return __int_as_float(__builtin_amdgcn_readlane(__float_as_int(v), l));
}

// feature c of node-slot i (both compile-time): lives in lane i*16+(c>>2), comp c&3
__device__ __forceinline__ float slotb(const float4& a, int i, int c) {
  int sl = i * 16 + (c >> 2);
  switch (c & 3) {
    case 0: return rl(a.x, sl);
    case 1: return rl(a.y, sl);
    case 2: return rl(a.z, sl);
    default: return rl(a.w, sl);
  }
}

// accumulate 4 fp16 values (packed in uint2) into a float4
__device__ __forceinline__ void addh4(float4& a, uint2 q) {
  float2 f0 = __half22float2(__builtin_bit_cast(__half2, q.x));
  float2 f1 = __half22float2(__builtin_bit_cast(__half2, q.y));
  a.x += f0.x; a.y += f0.y; a.z += f1.x; a.w += f1.y;
}

__device__ __forceinline__ void acc4(float4& a, const float4& v) {
  a.x += v.x; a.y += v.y; a.z += v.z; a.w += v.w;
}

__device__ __forceinline__ unsigned short f2h(float v) {
  return __builtin_bit_cast(unsigned short, __float2half(v));
}

__device__ __forceinline__ __half2 pack2(float a, float b) {
  return __halves2half2(__float2half(a), __float2half(b));
}

// ---------------- CSR build ----------------

__global__ __launch_bounds__(256) void k_degree(const int* __restrict__ dst,
                                                int* __restrict__ deg) {
  int i = blockIdx.x * 256 + threadIdx.x;
  if (i < EE) atomicAdd(&deg[dst[i]], 1);
}

__global__ __launch_bounds__(256) void k_part(const int* __restrict__ deg,
                                              int* __restrict__ partial) {
  int i = blockIdx.x * 256 + threadIdx.x;
  int v = (i < NN) ? deg[i] : 0;
#pragma unroll
  for (int off = 1; off < 64; off <<= 1) v += __shfl_xor(v, off);
  __shared__ int wsum[4];
  if ((threadIdx.x & 63) == 0) wsum[threadIdx.x >> 6] = v;
  __syncthreads();
  if (threadIdx.x == 0) partial[blockIdx.x] = wsum[0] + wsum[1] + wsum[2] + wsum[3];
}

__global__ __launch_bounds__(256) void k_scanp(const int* __restrict__ partial,
                                               int* __restrict__ chunkbase) {
  __shared__ int sc[256];
  int t = threadIdx.x;
  int v = (t < NCHUNK) ? partial[t] : 0;
  sc[t] = v;
  __syncthreads();
  for (int off = 1; off < 256; off <<= 1) {
    int u = (t >= off) ? sc[t - off] : 0;
    __syncthreads();
    sc[t] += u;
    __syncthreads();
  }
  if (t < NCHUNK) chunkbase[t] = sc[t] - v;  // exclusive
}

__global__ __launch_bounds__(256) void k_rows(const int* __restrict__ deg,
                                              const int* __restrict__ chunkbase,
                                              int* __restrict__ rowstart,
                                              float* __restrict__ dinv,
                                              int* __restrict__ cursor) {
  __shared__ int sc[256];
  int t = threadIdx.x;
  int i = blockIdx.x * 256 + t;
  int d = (i < NN) ? deg[i] : 0;
  sc[t] = d;
  __syncthreads();
  for (int off = 1; off < 256; off <<= 1) {
    int u = (t >= off) ? sc[t - off] : 0;
    __syncthreads();
    sc[t] += u;
    __syncthreads();
  }
  if (i < NN) {
    rowstart[i] = chunkbase[blockIdx.x] + sc[t] - d;
    dinv[i] = (d > 0) ? rsqrtf((float)d) : 0.f;
    cursor[i] = 0;
  }
  if (blockIdx.x == 0 && t == 0) rowstart[NN] = EE;
}

__global__ __launch_bounds__(256) void k_fill(const int* __restrict__ src,
                                              const int* __restrict__ dst,
                                              const int* __restrict__ rowstart,
                                              int* __restrict__ cursor,
                                              int* __restrict__ csr) {
  int i = blockIdx.x * 256 + threadIdx.x;
  if (i < EE) {
    int d = dst[i];
    int pos = rowstart[d] + atomicAdd(&cursor[d], 1);
    csr[pos] = src[i];
  }
}

// ---------------- xd = x * dinv[n] ----------------

__global__ __launch_bounds__(256) void k_xd(const float* __restrict__ x,
                                            const float* __restrict__ dinv,
                                            float* __restrict__ xd) {
  int i = blockIdx.x * 256 + threadIdx.x;  // over NN*16 float4s
  if (i < NN * 16) {
    int n = i >> 4;
    float d = dinv[n];
    float4 v = ((const float4*)x)[i];
    v.x *= d; v.y *= d; v.z *= d; v.w *= d;
    ((float4*)xd)[i] = v;
  }
}

// ---------------- agg(xd) * dinv[n] -> aggxs [N,64] fp32 ----------------

__global__ __launch_bounds__(256) void k_aggx(const float* __restrict__ xd,
                                              const float* __restrict__ dinv,
                                              const int* __restrict__ rowstart,
                                              const int* __restrict__ csr,
                                              float* __restrict__ outp) {
  int lane = threadIdx.x & 63;
  int f4 = lane & 15, es = lane >> 4;
  int wg = (blockIdx.x * 256 + threadIdx.x) >> 6;
  int nwv = (gridDim.x * 256) >> 6;
  const float4* x4 = (const float4*)xd;
  for (int g = wg; g < NG; g += nwv) {
    int n = g * 4 + es;
    int j = rowstart[n], end = rowstart[n + 1];
    float4 a = {0.f, 0.f, 0.f, 0.f}, b = {0.f, 0.f, 0.f, 0.f};
    for (; j + 1 < end; j += 2) {
      int s0 = csr[j], s1 = csr[j + 1];
      acc4(a, x4[(size_t)s0 * 16 + f4]);
      acc4(b, x4[(size_t)s1 * 16 + f4]);
    }
    if (j < end) {
      int s = csr[j];
      acc4(a, x4[(size_t)s * 16 + f4]);
    }
    acc4(a, b);
    float dn = dinv[n];
    a.x *= dn; a.y *= dn; a.z *= dn; a.w *= dn;
    ((float4*)outp)[(size_t)n * 16 + f4] = a;
  }
}

// ---------------- ARMA1 t=0, both stacks -> root01 fp32, s01h fp16 ----------------
// LDS: weights half2 packed by stack -> 32KB total.

__global__ __launch_bounds__(256) void k_t0(const float* __restrict__ x,
                                            const float* __restrict__ aggxs,
                                            const float* __restrict__ initW,
                                            const float* __restrict__ rootW,
                                            const float* __restrict__ bias,
                                            const float* __restrict__ dinv,
                                            float* __restrict__ root01,
                                            unsigned short* __restrict__ s01h) {
  __shared__ __half2 Wi2[4096];
  __shared__ __half2 Wr2[4096];
  for (int i = threadIdx.x; i < 4096; i += 256) {
    Wi2[i] = pack2(initW[i], initW[4096 + i]);
    Wr2[i] = pack2(rootW[i], rootW[4096 + i]);
  }
  __syncthreads();
  int lane = threadIdx.x & 63;
  float b_0 = bias[lane], b_1 = bias[64 + lane];
  int wid = (blockIdx.x * 256 + threadIdx.x) >> 6;
  int nw = (gridDim.x * 256) >> 6;
  for (int n = wid; n < NN; n += nw) {
    float dn = dinv[n];
    float xv = x[(size_t)n * 64 + lane];
    float gv = aggxs[(size_t)n * 64 + lane];
    float r0 = b_0, r1 = b_1;
    float i0 = 0.f, i1 = 0.f;
#pragma unroll
    for (int c = 0; c < 64; c++) {
      float xc = rl(xv, c), gc = rl(gv, c);
      float2 wr = __half22float2(Wr2[c * 64 + lane]);
      float2 wi = __half22float2(Wi2[c * 64 + lane]);
      r0 = fmaf(xc, wr.x, r0);
      r1 = fmaf(xc, wr.y, r1);
      i0 = fmaf(gc, wi.x, i0);
      i1 = fmaf(gc, wi.y, i1);
    }
    size_t b = (size_t)n * 128 + lane;
    root01[b] = r0;
    root01[b + 64] = r1;
    s01h[b] = f2h(fmaxf(i0 + r0, 0.f) * dn);
    s01h[b + 64] = f2h(fmaxf(i1 + r1, 0.f) * dn);
  }
}

// ---------------- ARMA1 t=1 fused: gather s01h + GEMM + h (4 nodes/wave) ----------
// LDS: W half2 packed by stack -> 16KB; one read = both stacks' weights.

__global__ __launch_bounds__(256) void k_t1(const unsigned short* __restrict__ s01h,
                                            const float* __restrict__ root01,
                                            const float* __restrict__ W,
                                            const float* __restrict__ dinv,
                                            const int* __restrict__ rowstart,
                                            const int* __restrict__ csr,
                                            float* __restrict__ h,
                                            unsigned short* __restrict__ hsh) {
  __shared__ __half2 Wh2[4096];
  for (int i = threadIdx.x; i < 4096; i += 256)
    Wh2[i] = pack2(W[i], W[4096 + i]);
  __syncthreads();
  int lane = threadIdx.x & 63;
  int f4 = lane & 15, es = lane >> 4;
  int wg = (blockIdx.x * 256 + threadIdx.x) >> 6;
  int nwv = (gridDim.x * 256) >> 6;
  for (int g = wg; g < NG; g += nwv) {
    int base = g * 4;
    int n = base + es;
    int j = rowstart[n], end = rowstart[n + 1];
    float4 a = {0.f, 0.f, 0.f, 0.f}, b = {0.f, 0.f, 0.f, 0.f};
    for (; j + 1 < end; j += 2) {
      int s0 = csr[j], s1 = csr[j + 1];
      const uint2* r0 = (const uint2*)(s01h + (size_t)s0 * 128);
      const uint2* r1 = (const uint2*)(s01h + (size_t)s1 * 128);
      uint2 q00 = r0[f4], q01 = r0[16 + f4];
      uint2 q10 = r1[f4], q11 = r1[16 + f4];
      addh4(a, q00); addh4(b, q01);
      addh4(a, q10); addh4(b, q11);
    }
    if (j < end) {
      int s = csr[j];
      const uint2* r = (const uint2*)(s01h + (size_t)s * 128);
      addh4(a, r[f4]); addh4(b, r[16 + f4]);
    }
    // GEMM: 4 nodes share each LDS weight read; 1 read = both stacks
    float c0[4] = {0.f, 0.f, 0.f, 0.f}, c1[4] = {0.f, 0.f, 0.f, 0.f};
#pragma unroll
    for (int c = 0; c < 64; c++) {
      float2 w = __half22float2(Wh2[c * 64 + lane]);
#pragma unroll
      for (int i = 0; i < 4; i++) {
        c0[i] = fmaf(slotb(a, i, c), w.x, c0[i]);
        c1[i] = fmaf(slotb(b, i, c), w.y, c1[i]);
      }
    }
    float dnl = dinv[n];
#pragma unroll
    for (int i = 0; i < 4; i++) {
      float dni = rl(dnl, i * 16);
      size_t bb = (size_t)(base + i) * 128 + lane;
      float o0 = fmaxf(fmaf(dni, c0[i], root01[bb]), 0.f);
      float o1 = fmaxf(fmaf(dni, c1[i], root01[bb + 64]), 0.f);
      float hv = 0.5f * (o0 + o1);
      h[(size_t)(base + i) * 64 + lane] = hv;
      hsh[(size_t)(base + i) * 64 + lane] = f2h(hv * dni);
    }
  }
}

// ---------------- ARMA2 t=0 fused: gather hsh + GEMM (stacks packed) ----------------
// LDS: weights half2 packed BY STACK (lane selects its k once per read) -> 16KB.
// Inner loop = round-11 structure (1 fma per c per node) to keep VGPR ~50.

__global__ __launch_bounds__(256) void k2_t0(const float* __restrict__ h,
                                             const unsigned short* __restrict__ hsh,
                                             const float* __restrict__ initW2,
                                             const float* __restrict__ rootW2,
                                             const float* __restrict__ b2,
                                             const float* __restrict__ dinv,
                                             const int* __restrict__ rowstart,
                                             const int* __restrict__ csr,
                                             float* __restrict__ root2,
                                             unsigned short* __restrict__ s2h) {
  __shared__ __half2 Wi2[2048];  // [c][col], .x = k0, .y = k1
  __shared__ __half2 Wr2[2048];
  for (int idx = threadIdx.x; idx < 2048; idx += 256) {
    Wi2[idx] = pack2(initW2[idx], initW2[2048 + idx]);
    Wr2[idx] = pack2(rootW2[idx], rootW2[2048 + idx]);
  }
  __syncthreads();
  int lane = threadIdx.x & 63;
  int f4 = lane & 15, es = lane >> 4;
  int k = lane >> 5, col = lane & 31;
  float bv = b2[lane];
  int wg = (blockIdx.x * 256 + threadIdx.x) >> 6;
  int nwv = (gridDim.x * 256) >> 6;
  for (int g = wg; g < NG; g += nwv) {
    int base = g * 4;
    int n = base + es;
    int j = rowstart[n], end = rowstart[n + 1];
    float4 a = {0.f, 0.f, 0.f, 0.f}, b = {0.f, 0.f, 0.f, 0.f};
    for (; j + 1 < end; j += 2) {
      int s0 = csr[j], s1 = csr[j + 1];
      addh4(a, ((const uint2*)(hsh + (size_t)s0 * 64))[f4]);
      addh4(b, ((const uint2*)(hsh + (size_t)s1 * 64))[f4]);
    }
    if (j < end) {
      int s = csr[j];
      addh4(a, ((const uint2*)(hsh + (size_t)s * 64))[f4]);
    }
    acc4(a, b);
    float hv[4];
#pragma unroll
    for (int i = 0; i < 4; i++) hv[i] = h[(size_t)(base + i) * 64 + lane];
    float aR[4] = {bv, bv, bv, bv}, aI[4] = {0.f, 0.f, 0.f, 0.f};
#pragma unroll
    for (int c = 0; c < 64; c++) {
      float2 wrf = __half22float2(Wr2[c * 32 + col]);
      float2 wif = __half22float2(Wi2[c * 32 + col]);
      float wr = k ? wrf.y : wrf.x;
      float wi = k ? wif.y : wif.x;
#pragma unroll
      for (int i = 0; i < 4; i++) {
        aR[i] = fmaf(rl(hv[i], c), wr, aR[i]);
        aI[i] = fmaf(slotb(a, i, c), wi, aI[i]);
      }
    }
    float dnl = dinv[n];
#pragma unroll
    for (int i = 0; i < 4; i++) {
      float dni = rl(dnl, i * 16);
      float o = fmaxf(fmaf(dni, aI[i], aR[i]), 0.f);
      root2[(size_t)(base + i) * 64 + lane] = aR[i];
      s2h[(size_t)(base + i) * 64 + lane] = f2h(o * dni);
    }
  }
}

// ---------------- ARMA2 t=1 fused: gather s2h + GEMM + mean -> out ----------------
// LDS: weights half2 packed BY STACK -> 2KB. Round-11 inner loop structure.

__global__ __launch_bounds__(256) void k2_t1(const unsigned short* __restrict__ s2h,
                                             const float* __restrict__ root2,
                                             const float* __restrict__ W2,
                                             const float* __restrict__ dinv,
                                             const int* __restrict__ rowstart,
                                             const int* __restrict__ csr,
                                             float* __restrict__ outp) {
  __shared__ __half2 Ws2[1024];  // [c][col], .x = k0, .y = k1
  for (int idx = threadIdx.x; idx < 1024; idx += 256)
    Ws2[idx] = pack2(W2[idx], W2[1024 + idx]);
  __syncthreads();
  int lane = threadIdx.x & 63;
  int f4 = lane & 15, es = lane >> 4;
  int k = lane >> 5, col = lane & 31;
  int wg = (blockIdx.x * 256 + threadIdx.x) >> 6;
  int nwv = (gridDim.x * 256) >> 6;
  for (int g = wg; g < NG; g += nwv) {
    int base = g * 4;
    int n = base + es;
    int j = rowstart[n], end = rowstart[n + 1];
    float4 a = {0.f, 0.f, 0.f, 0.f}, b = {0.f, 0.f, 0.f, 0.f};
    for (; j + 1 < end; j += 2) {
      int s0 = csr[j], s1 = csr[j + 1];
      addh4(a, ((const uint2*)(s2h + (size_t)s0 * 64))[f4]);
      addh4(b, ((const uint2*)(s2h + (size_t)s1 * 64))[f4]);
    }
    if (j < end) {
      int s = csr[j];
      addh4(a, ((const uint2*)(s2h + (size_t)s * 64))[f4]);
    }
    acc4(a, b);
    float acc[4] = {0.f, 0.f, 0.f, 0.f};
#pragma unroll
    for (int c = 0; c < 32; c++) {
      float2 wf = __half22float2(Ws2[c * 32 + col]);
      float w = k ? wf.y : wf.x;
#pragma unroll
      for (int i = 0; i < 4; i++) {
        float p0 = slotb(a, i, c);
        float p1 = slotb(a, i, 32 + c);
        float pc = (lane < 32) ? p0 : p1;
        acc[i] = fmaf(pc, w, acc[i]);
      }
    }
    float dnl = dinv[n];
#pragma unroll
    for (int i = 0; i < 4; i++) {
      float dni = rl(dnl, i * 16);
      float o = fmaxf(fmaf(dni, acc[i], root2[(size_t)(base + i) * 64 + lane]), 0.f);
      o += __shfl_xor(o, 32);
      if (lane < 32) outp[(size_t)(base + i) * 32 + col] = 0.5f * o;
    }
  }
}

// ---------------- host launch ----------------

extern "C" void kernel_launch(void* const* d_in, const int* in_sizes, int n_in,
                              void* d_out, int out_size, void* d_ws, size_t ws_size,
                              hipStream_t stream) {
  const float* x = (const float*)d_in[0];
  const int* edge_index = (const int*)d_in[1];
  const float* initW1 = (const float*)d_in[2];
  const float* w1 = (const float*)d_in[3];
  const float* rootW1 = (const float*)d_in[4];
  const float* b1 = (const float*)d_in[5];
  const float* initW2 = (const float*)d_in[6];
  const float* w2 = (const float*)d_in[7];
  const float* rootW2 = (const float*)d_in[8];
  const float* b2 = (const float*)d_in[9];
  float* out = (float*)d_out;

  const int* src = edge_index;
  const int* dst = edge_index + EE;

  size_t off = 0;
  auto carve = [&](size_t bytes) {
    size_t r = off;
    off = (off + bytes + 255) & ~(size_t)255;
    return r;
  };
  char* ws = (char*)d_ws;
  int* deg = (int*)(ws + carve((size_t)NN * 4));
  int* rowstart = (int*)(ws + carve((size_t)(NN + 1) * 4));
  int* csr = (int*)(ws + carve((size_t)EE * 4));
  float* dinv = (float*)(ws + carve((size_t)NN * 4));
  int* cursor = (int*)(ws + carve((size_t)NN * 4));
  int* partial = (int*)(ws + carve(256 * 4));
  int* chunkbase = (int*)(ws + carve(256 * 4));
  float* Bxd = (float*)(ws + carve((size_t)NN * 64 * 4));            // xd
  float* B1 = (float*)(ws + carve((size_t)NN * 64 * 4));             // aggxs, later h
  float* B2 = (float*)(ws + carve((size_t)NN * 128 * 4));            // root01, later root2
  unsigned short* H1 = (unsigned short*)(ws + carve((size_t)NN * 128 * 2));  // s01h, later s2h
  unsigned short* H2 = (unsigned short*)(ws + carve((size_t)NN * 64 * 2));   // hsh
  (void)ws_size; (void)in_sizes; (void)n_in; (void)out_size;

  const int EB = (EE + 255) / 256;

  hipMemsetAsync(deg, 0, (size_t)NN * 4, stream);
  k_degree<<<EB, 256, 0, stream>>>(dst, deg);
  k_part<<<NCHUNK, 256, 0, stream>>>(deg, partial);
  k_scanp<<<1, 256, 0, stream>>>(partial, chunkbase);
  k_rows<<<NCHUNK, 256, 0, stream>>>(deg, chunkbase, rowstart, dinv, cursor);
  k_fill<<<EB, 256, 0, stream>>>(src, dst, rowstart, cursor, csr);

  k_xd<<<(NN * 16 + 255) / 256, 256, 0, stream>>>(x, dinv, Bxd);
  k_aggx<<<3125, 256, 0, stream>>>(Bxd, dinv, rowstart, csr, B1);
  k_t0<<<1280, 256, 0, stream>>>(x, B1, initW1, rootW1, b1, dinv, B2, H1);
  k_t1<<<3125, 256, 0, stream>>>(H1, B2, w1, dinv, rowstart, csr, B1, H2);
  k2_t0<<<3125, 256, 0, stream>>>(B1, H2, initW2, rootW2, b2, dinv, rowstart, csr, B2, H1);
  k2_t1<<<3125, 256, 0, stream>>>(H1, B2, w2, dinv, rowstart, csr, out);
}